// Round 1
// baseline (371.169 us; speedup 1.0000x reference)
//
#include <hip/hip_runtime.h>

// Problem constants (fixed by the reference setup)
#define Bd 4
#define Cd 64
#define Hd 512
#define Wd 512
#define HWp (Hd * Wd)        // 262144 pixels per image
#define NSd 2048
#define NLd 1000

// ---------------------------------------------------------------------------
// Kernel 1: per-(b, c) label-sum histogram.
// grid = (chunks=4, C, B), block = 256 threads.
// Each block processes HW/4 pixels of one (b,c) plane via float4 loads,
// accumulates into a 1000-entry LDS histogram with LDS atomics, then flushes
// with coalesced global atomics into sums[b][c][l].
// ---------------------------------------------------------------------------
__global__ __launch_bounds__(256)
void sums_kernel(const float* __restrict__ x, const int* __restrict__ lab,
                 float* __restrict__ sums) {
    __shared__ float lsum[NLd];
    const int tid   = threadIdx.x;
    const int chunk = blockIdx.x;   // 0..3
    const int c     = blockIdx.y;   // 0..63
    const int b     = blockIdx.z;   // 0..3

    for (int l = tid; l < NLd; l += 256) lsum[l] = 0.0f;
    __syncthreads();

    const float4* __restrict__ xp =
        (const float4*)x + (size_t)(b * Cd + c) * (HWp / 4);
    const int4* __restrict__ lp =
        (const int4*)lab + (size_t)b * (HWp / 4);

    const int nvec  = HWp / 4 / 4;        // 16384 float4 per chunk
    const int v0    = chunk * nvec;
    const int v1    = v0 + nvec;
    for (int v = v0 + tid; v < v1; v += 256) {
        float4 xv = xp[v];
        int4   lv = lp[v];
        atomicAdd(&lsum[lv.x], xv.x);
        atomicAdd(&lsum[lv.y], xv.y);
        atomicAdd(&lsum[lv.z], xv.z);
        atomicAdd(&lsum[lv.w], xv.w);
    }
    __syncthreads();

    float* __restrict__ dst = sums + (size_t)(b * Cd + c) * NLd;
    for (int l = tid; l < NLd; l += 256) {
        atomicAdd(&dst[l], lsum[l]);
    }
}

// ---------------------------------------------------------------------------
// Kernel 2: per-image label counts. grid = (chunks=4, B), block = 256.
// ---------------------------------------------------------------------------
__global__ __launch_bounds__(256)
void counts_kernel(const int* __restrict__ lab, float* __restrict__ counts) {
    __shared__ unsigned lcnt[NLd];
    const int tid   = threadIdx.x;
    const int chunk = blockIdx.x;   // 0..3
    const int b     = blockIdx.y;   // 0..3

    for (int l = tid; l < NLd; l += 256) lcnt[l] = 0u;
    __syncthreads();

    const int4* __restrict__ lp = (const int4*)lab + (size_t)b * (HWp / 4);
    const int nvec = HWp / 4 / 4;   // 16384
    const int v0   = chunk * nvec;
    const int v1   = v0 + nvec;
    for (int v = v0 + tid; v < v1; v += 256) {
        int4 lv = lp[v];
        atomicAdd(&lcnt[lv.x], 1u);
        atomicAdd(&lcnt[lv.y], 1u);
        atomicAdd(&lcnt[lv.z], 1u);
        atomicAdd(&lcnt[lv.w], 1u);
    }
    __syncthreads();

    float* __restrict__ dst = counts + (size_t)b * NLd;
    for (int l = tid; l < NLd; l += 256) {
        atomicAdd(&dst[l], (float)lcnt[l]);
    }
}

// ---------------------------------------------------------------------------
// Kernel 3: gather means at edge endpoints + copy edge weights.
// One thread per (b, s, c) output element; t = ((b*NS)+s)*C + c.
// out layout: [xa | xb | y] flat (B*NS*C, B*NS*C, B*NS).
// ---------------------------------------------------------------------------
__global__ __launch_bounds__(256)
void gather_kernel(const float* __restrict__ sums,
                   const float* __restrict__ counts,
                   const int* __restrict__ edges,
                   const float* __restrict__ ew,
                   float* __restrict__ out) {
    const int t  = blockIdx.x * 256 + threadIdx.x;   // 0 .. B*NS*C-1
    const int bs = t / Cd;                            // b*NS + s
    const int c  = t % Cd;
    const int b  = bs / NSd;

    const int la = edges[bs * 2 + 0];
    const int lb = edges[bs * 2 + 1];

    const float ca = fmaxf(counts[b * NLd + la], 1.0f);
    const float cb = fmaxf(counts[b * NLd + lb], 1.0f);

    const size_t plane = (size_t)(b * Cd + c) * NLd;
    const float va = sums[plane + la] / ca;
    const float vb = sums[plane + lb] / cb;

    out[t] = va;
    out[(size_t)Bd * NSd * Cd + t] = vb;
    if (t < Bd * NSd) {
        out[2 * (size_t)Bd * NSd * Cd + t] = ew[t];
    }
}

extern "C" void kernel_launch(void* const* d_in, const int* in_sizes, int n_in,
                              void* d_out, int out_size, void* d_ws, size_t ws_size,
                              hipStream_t stream) {
    const float* x     = (const float*)d_in[0];   // [B,C,H,W] f32
    const int*   lab   = (const int*)d_in[1];     // [B,1,H,W] i32
    const int*   edges = (const int*)d_in[2];     // [B,NS,2] i32
    const float* ew    = (const float*)d_in[3];   // [B,NS] f32
    float*       out   = (float*)d_out;

    float* sums   = (float*)d_ws;                         // [B,C,NL]
    float* counts = sums + (size_t)Bd * Cd * NLd;         // [B,NL]

    const size_t ws_needed = ((size_t)Bd * Cd * NLd + (size_t)Bd * NLd) * sizeof(float);
    hipMemsetAsync(d_ws, 0, ws_needed, stream);

    sums_kernel<<<dim3(4, Cd, Bd), 256, 0, stream>>>(x, lab, sums);
    counts_kernel<<<dim3(4, Bd), 256, 0, stream>>>(lab, counts);

    const int n_gather = Bd * NSd * Cd;   // 524288
    gather_kernel<<<n_gather / 256, 256, 0, stream>>>(sums, counts, edges, ew, out);
}